// Round 23
// baseline (1035.159 us; speedup 1.0000x reference)
//
#include <hip/hip_runtime.h>
#include <hip/hip_bf16.h>
#include <math.h>

#define BATCH 32
#define TSEQ 1024
#define DMODEL 1024
#define KEXP 8
#define FFFN 4096
#define EEMB 64
#define RHID 128
#define NSTAGE 5
#define NVIEW 4

typedef float f32x4 __attribute__((ext_vector_type(4)));
typedef __bf16 bf16x8 __attribute__((ext_vector_type(8)));

#define AS1C(p) ((const __attribute__((address_space(1))) unsigned int*)(p))
#define AS3(p)  ((__attribute__((address_space(3))) unsigned int*)(p))

__device__ __forceinline__ unsigned short f32_to_bf16_rne(float f) {
    union { float f; unsigned int u; } v; v.f = f;
    unsigned int u = v.u;
    unsigned int r = u + 0x7FFFu + ((u >> 16) & 1u);
    return (unsigned short)(r >> 16);
}

__device__ int resolve_id_one(const int* __restrict__ raw, int b, int hi, int is64) {
    int v = is64 ? raw[2 * b] : raw[b];
    return v < 0 ? 0 : (v >= hi ? hi - 1 : v);
}
__device__ int ids_are_64(const int* __restrict__ raw, int hi) {
    bool is64 = true;
    for (int i = 1; i < 32; i += 2) is64 = is64 && (raw[i] == 0);
    for (int i = 0; i < 32; i += 2) is64 = is64 && (raw[i] >= 0 && raw[i] < hi);
    return is64 ? 1 : 0;
}

// ---------- router stage 1: one block per sample (grid=32), fp64 exact ----------
__global__ __launch_bounds__(RHID) void router_probs_r23(
    const int* __restrict__ stage_ids,
    const int* __restrict__ view_ids,
    const float* __restrict__ stage_emb,
    const float* __restrict__ view_emb,
    const float* __restrict__ rw1,
    const float* __restrict__ rb1,
    const float* __restrict__ rw2,
    const float* __restrict__ rb2,
    float* __restrict__ out_probs,
    float* __restrict__ out_sel,
    int* __restrict__ sel_ws)
{
    const int b = blockIdx.x;
    const int t = threadIdx.x;
    __shared__ double z[2 * EEMB];
    __shared__ double h[RHID];
    __shared__ double lg[KEXP];
    __shared__ int sid_s, vid_s;
    if (t == 0) {
        const int s64 = ids_are_64(stage_ids, NSTAGE);
        const int v64 = ids_are_64(view_ids, NVIEW);
        sid_s = resolve_id_one(stage_ids, b, NSTAGE, s64);
        vid_s = resolve_id_one(view_ids, b, NVIEW, v64);
    }
    __syncthreads();
    const int sid = sid_s, vid = vid_s;
    z[t] = (t < EEMB) ? (double)stage_emb[sid * EEMB + t]
                      : (double)view_emb[vid * EEMB + (t - EEMB)];
    __syncthreads();
    double acc = (double)rb1[t];
    for (int i = 0; i < 2 * EEMB; ++i) acc += z[i] * (double)rw1[i * RHID + t];
    h[t] = fmax(acc, 0.0);
    __syncthreads();
    if (t < KEXP) {
        double a = (double)rb2[t];
        for (int i = 0; i < RHID; ++i) a += h[i] * (double)rw2[i * KEXP + t];
        lg[t] = a;
    }
    __syncthreads();
    if (t == 0) {
        double mx = lg[0]; int am = 0;
        for (int k = 1; k < KEXP; ++k) if (lg[k] > mx) { mx = lg[k]; am = k; }
        double p[KEXP]; double den = 0.0;
        for (int k = 0; k < KEXP; ++k) { p[k] = exp(lg[k] - mx); den += p[k]; }
        for (int k = 0; k < KEXP; ++k) out_probs[b * KEXP + k] = (float)(p[k] / den);
        out_sel[b] = (float)am;
        sel_ws[b] = am;
    }
}

__global__ void router_loss_r23(const float* __restrict__ probs,
                                const int* __restrict__ sel,
                                float* __restrict__ out_loss)
{
    if (threadIdx.x != 0) return;
    double loss = 0.0;
    for (int k = 0; k < KEXP; ++k) {
        double ps = 0.0; int fc = 0;
        for (int b = 0; b < BATCH; ++b) {
            ps += (double)probs[b * KEXP + k];
            fc += (sel[b] == k) ? 1 : 0;
        }
        loss += ((double)fc / (double)BATCH) * (ps / (double)BATCH);
    }
    out_loss[0] = (float)((double)KEXP * loss);
}

// ---------------- prep: f32 -> bf16 convert (x) ----------------
__global__ void cvt_f32_bf16_r23(const float* __restrict__ src,
                                 unsigned short* __restrict__ dst, size_t n)
{
    size_t i = (size_t)blockIdx.x * blockDim.x + threadIdx.x;
    size_t stride = (size_t)gridDim.x * blockDim.x;
    for (size_t j = i * 4; j < n; j += stride * 4) {
        float4 v = *(const float4*)(src + j);
        ushort4 o;
        o.x = f32_to_bf16_rne(v.x); o.y = f32_to_bf16_rne(v.y);
        o.z = f32_to_bf16_rne(v.z); o.w = f32_to_bf16_rne(v.w);
        *(ushort4*)(dst + j) = o;
    }
}

// ------ prep: 64x64 tiled transpose+convert src[e][R][C] f32 -> dst[e][C][R] bf16 ------
__global__ __launch_bounds__(512) void transpose_f32_bf16_r23(
    const float* __restrict__ src, unsigned short* __restrict__ dst, int R, int C)
{
    __shared__ float tile[64][65];
    const int e = blockIdx.z;
    const float* s = src + (size_t)e * R * C;
    unsigned short* d = dst + (size_t)e * R * C;
    const int c0 = blockIdx.x * 64, r0 = blockIdx.y * 64;
    const int tx = threadIdx.x, ty = threadIdx.y; // (64, 8)
    #pragma unroll
    for (int i = 0; i < 64; i += 8)
        tile[ty + i][tx] = s[(size_t)(r0 + ty + i) * C + (c0 + tx)];
    __syncthreads();
    #pragma unroll
    for (int i = 0; i < 64; i += 8)
        d[(size_t)(c0 + ty + i) * R + (r0 + tx)] = f32_to_bf16_rne(tile[tx][ty + i]);
}

// ==== 256x256 / BK=32 / 2-buffer 64KB / 2-phase-per-tile / 2 blocks/CU GEMM ====
// C = A @ BT^T (+bias [,gelu]).  A: [z][M][K] bf16, BT: [KEXP][N][K] bf16.
// Combines the two HW-proven levers: phase-split schedule (r22: -7% wall) AND
// >=2 co-resident blocks/CU (r17's occupancy law: barrier/vmcnt drains absorbed
// by the other block). LDS 64KB = 2 buf x (A 16KB + B 16KB); rows 64B.
// r12-VERIFIED zero-conflict swizzle: read chunk fq^((fr>>1)&3); staging source
// chunk (lane&3)^((lane>>3)&3); linear gload_lds dest (rule #21).
// Per tile: ph0 {read B[4]+A[0..3] | stage A(t+1) | bar,lgkm | 16 MFMA | bar}
//           ph1 {read A[4..7]      | stage B(t+1), vmcnt(0) | bar,lgkm | 16 MFMA | bar}

template<int MODE, int OBF>  // MODE 0: gelu(acc+bias); 1: acc+bias. OBF: 1 bf16 out, 0 f32 out
__global__ __launch_bounds__(512, 2) void gemm_2p_r23(
    const unsigned short* __restrict__ Aall,
    const unsigned short* __restrict__ BTall,
    const float* __restrict__ biasAll,
    void* __restrict__ OutV,
    const int* __restrict__ sel, int g0,
    int M, int N, int K)
{
    const int bz = blockIdx.z;
    int e = sel[g0 + bz];
    e = e < 0 ? 0 : (e >= KEXP ? KEXP - 1 : e);
    const unsigned short* A  = Aall + (size_t)bz * M * K;
    const unsigned short* BT = BTall + (size_t)e * (size_t)N * K;
    const float* bias = biasAll + (size_t)e * N;

    __shared__ __align__(16) unsigned short lds[32768];   // 64 KB
    char* Lc = (char*)lds;

    const int tid  = threadIdx.x;
    const int lane = tid & 63;
    const int wave = tid >> 6;     // 0..7
    const int wr = wave >> 2;      // 0..1 : 128 output rows
    const int wc = wave & 3;       // 0..3 : 64 output cols
    const int fr = lane & 15;
    const int fq = lane >> 4;

    const int brow = blockIdx.y * 256;
    const int bcol = blockIdx.x * 256;

    // staging: unit = 16KB (256 rows x 64B); 16 wave-chunks of 1KB (16 rows each).
    const int srow = lane >> 2;                                 // 0..15
    const int scol = ((lane & 3) ^ ((lane >> 3) & 3)) * 8;      // pre-swizzled (hw)
    // read-side swizzled chunk byte offset (zero-conflict, r12-verified)
    const int coff = (fq ^ ((fr >> 1) & 3)) * 16;

    const int NT = K >> 5;

    const f32x4 zero = {0.f, 0.f, 0.f, 0.f};
    f32x4 acc[8][4];
    #pragma unroll
    for (int m = 0; m < 8; ++m)
        #pragma unroll
        for (int n = 0; n < 4; ++n) acc[m][n] = zero;

    // stage matrix (isB) of tile t: 2 gloads/thread (16KB unit)
    auto STAGE = [&](int isB, int t) {
        const int kh = t << 5;
        char* dbase = Lc + (t & 1) * 32768 + isB * 16384 + wave * 1024;
        const unsigned short* sbase = isB ? (BT + (size_t)bcol * K) : (A + (size_t)brow * K);
        #pragma unroll
        for (int j = 0; j < 2; ++j) {
            const int r0 = (j * 8 + wave) * 16;
            const unsigned short* g = sbase + (size_t)(r0 + srow) * K + (kh + scol);
            __builtin_amdgcn_global_load_lds(AS1C(g), AS3(dbase + j * 8192), 16, 0, 0);
        }
    };

    // prologue: tile 0 staged, drained
    STAGE(0, 0); STAGE(1, 0);
    asm volatile("s_waitcnt vmcnt(0)" ::: "memory");
    __builtin_amdgcn_s_barrier();
    __builtin_amdgcn_sched_barrier(0);

    for (int t = 0; t < NT; ++t) {
        const int aU = (t & 1) * 32768;
        const int bU = aU + 16384;
        const bool pf = (t + 1) < NT;

        // ======== phase 0: B frags + A[0..3]; stage A(t+1) ========
        bf16x8 bfr[4], af[4];
        #pragma unroll
        for (int n = 0; n < 4; ++n) {
            const int cb = wc * 64 + n * 16 + fr;
            bfr[n] = *(const bf16x8*)(Lc + bU + cb * 64 + coff);
        }
        #pragma unroll
        for (int m = 0; m < 4; ++m) {
            const int ra = wr * 128 + m * 16 + fr;
            af[m] = *(const bf16x8*)(Lc + aU + ra * 64 + coff);
        }
        if (pf) STAGE(0, t + 1);
        __builtin_amdgcn_sched_barrier(0);
        __builtin_amdgcn_s_barrier();
        asm volatile("s_waitcnt lgkmcnt(0)" ::: "memory");
        __builtin_amdgcn_sched_barrier(0);
        __builtin_amdgcn_s_setprio(1);
        #pragma unroll
        for (int m = 0; m < 4; ++m)
            #pragma unroll
            for (int n = 0; n < 4; ++n)
                acc[m][n] = __builtin_amdgcn_mfma_f32_16x16x32_bf16(af[m], bfr[n], acc[m][n], 0, 0, 0);
        __builtin_amdgcn_s_setprio(0);
        __builtin_amdgcn_s_barrier();

        // ======== phase 1: A[4..7]; stage B(t+1); tile-end drain ========
        bf16x8 ag[4];
        #pragma unroll
        for (int m = 0; m < 4; ++m) {
            const int ra = wr * 128 + (m + 4) * 16 + fr;
            ag[m] = *(const bf16x8*)(Lc + aU + ra * 64 + coff);
        }
        if (pf) STAGE(1, t + 1);
        if (pf) asm volatile("s_waitcnt vmcnt(0)" ::: "memory");   // t+1 resident (2nd block hides)
        __builtin_amdgcn_sched_barrier(0);
        __builtin_amdgcn_s_barrier();
        asm volatile("s_waitcnt lgkmcnt(0)" ::: "memory");
        __builtin_amdgcn_sched_barrier(0);
        __builtin_amdgcn_s_setprio(1);
        #pragma unroll
        for (int m = 0; m < 4; ++m)
            #pragma unroll
            for (int n = 0; n < 4; ++n)
                acc[m + 4][n] = __builtin_amdgcn_mfma_f32_16x16x32_bf16(ag[m], bfr[n], acc[m + 4][n], 0, 0, 0);
        __builtin_amdgcn_s_setprio(0);
        __builtin_amdgcn_s_barrier();
    }

    // epilogue: C/D col=lane&15, row=(lane>>4)*4+reg  [HW-verified rounds 8-22]
    #pragma unroll
    for (int m = 0; m < 8; ++m) {
        #pragma unroll
        for (int n = 0; n < 4; ++n) {
            #pragma unroll
            for (int r = 0; r < 4; ++r) {
                const int row = brow + wr * 128 + m * 16 + fq * 4 + r;
                const int col = bcol + wc * 64 + n * 16 + fr;
                float v = acc[m][n][r] + bias[col];
                if (MODE == 0) v = 0.5f * v * (1.0f + erff(v * 0.70710678118654752f));
                const size_t idx = (size_t)bz * M * N + (size_t)row * N + col;
                if (OBF) ((unsigned short*)OutV)[idx] = f32_to_bf16_rne(v);
                else     ((float*)OutV)[idx] = v;
            }
        }
    }
}

extern "C" void kernel_launch(void* const* d_in, const int* in_sizes, int n_in,
                              void* d_out, int out_size, void* d_ws, size_t ws_size,
                              hipStream_t stream)
{
    const float* x         = (const float*)d_in[0];
    const int*   stage_ids = (const int*)d_in[1];
    const int*   view_ids  = (const int*)d_in[2];
    const float* stage_emb = (const float*)d_in[3];
    const float* view_emb  = (const float*)d_in[4];
    const float* rw1       = (const float*)d_in[5];
    const float* rb1       = (const float*)d_in[6];
    const float* rw2       = (const float*)d_in[7];
    const float* rb2       = (const float*)d_in[8];
    const float* w1        = (const float*)d_in[9];
    const float* b1        = (const float*)d_in[10];
    const float* w2        = (const float*)d_in[11];
    const float* b2        = (const float*)d_in[12];

    float* out_f = (float*)d_out;
    const size_t OUT_ELEMS = (size_t)BATCH * TSEQ * DMODEL;

    const size_t MB64 = 67108864ull;
    char* ws = (char*)d_ws;
    int* sel_ws            = (int*)ws;
    unsigned short* x_bf   = (unsigned short*)(ws + 4096);
    unsigned short* w1T    = (unsigned short*)(ws + 4096 + MB64);
    unsigned short* w2T    = (unsigned short*)(ws + 4096 + 2 * MB64);
    unsigned short* h_bf   = (unsigned short*)(ws + 4096 + 3 * MB64);

    int grp = 1;
    {
        const size_t base = 4096 + 3 * MB64;
        const size_t avail = ws_size > base ? ws_size - base : 0;
        for (int g = 32; g >= 1; g >>= 1) {
            if ((size_t)g * TSEQ * FFFN * 2 <= avail) { grp = g; break; }
        }
    }

    router_probs_r23<<<BATCH, RHID, 0, stream>>>(stage_ids, view_ids, stage_emb, view_emb,
        rw1, rb1, rw2, rb2,
        out_f + OUT_ELEMS,
        out_f + OUT_ELEMS + BATCH * KEXP,
        sel_ws);
    router_loss_r23<<<1, 64, 0, stream>>>(out_f + OUT_ELEMS, sel_ws,
        out_f + OUT_ELEMS + BATCH * KEXP + BATCH);

    cvt_f32_bf16_r23<<<2048, 256, 0, stream>>>(x, x_bf, (size_t)BATCH * TSEQ * DMODEL);
    dim3 tb(64, 8);
    transpose_f32_bf16_r23<<<dim3(FFFN / 64, DMODEL / 64, KEXP), tb, 0, stream>>>(w1, w1T, DMODEL, FFFN);
    transpose_f32_bf16_r23<<<dim3(DMODEL / 64, FFFN / 64, KEXP), tb, 0, stream>>>(w2, w2T, FFFN, DMODEL);

    for (int g0 = 0; g0 < BATCH; g0 += grp) {
        // h = gelu(x @ w1[e]^T + b1[e]) : M=1024, N=4096, K=1024 -> bf16
        gemm_2p_r23<0, 1><<<dim3(FFFN / 256, TSEQ / 256, grp), 512, 0, stream>>>(
            x_bf + (size_t)g0 * TSEQ * DMODEL, w1T, b1,
            (void*)h_bf, sel_ws, g0, TSEQ, FFFN, DMODEL);
        // out = h @ w2[e]^T + b2[e]     : M=1024, N=1024, K=4096 -> f32
        gemm_2p_r23<1, 0><<<dim3(DMODEL / 256, TSEQ / 256, grp), 512, 0, stream>>>(
            h_bf, w2T, b2,
            (void*)(out_f + (size_t)g0 * TSEQ * DMODEL), sel_ws, g0, TSEQ, DMODEL, FFFN);
    }
}

// Round 24
// 779.699 us; speedup vs baseline: 1.3276x; 1.3276x over previous
//
#include <hip/hip_runtime.h>
#include <hip/hip_bf16.h>
#include <math.h>

#define BATCH 32
#define TSEQ 1024
#define DMODEL 1024
#define KEXP 8
#define FFFN 4096
#define EEMB 64
#define RHID 128
#define NSTAGE 5
#define NVIEW 4

typedef float f32x4 __attribute__((ext_vector_type(4)));
typedef __bf16 bf16x8 __attribute__((ext_vector_type(8)));

#define AS1C(p) ((const __attribute__((address_space(1))) unsigned int*)(p))
#define AS3(p)  ((__attribute__((address_space(3))) unsigned int*)(p))

__device__ __forceinline__ unsigned short f32_to_bf16_rne(float f) {
    union { float f; unsigned int u; } v; v.f = f;
    unsigned int u = v.u;
    unsigned int r = u + 0x7FFFu + ((u >> 16) & 1u);
    return (unsigned short)(r >> 16);
}

__device__ int resolve_id_one(const int* __restrict__ raw, int b, int hi, int is64) {
    int v = is64 ? raw[2 * b] : raw[b];
    return v < 0 ? 0 : (v >= hi ? hi - 1 : v);
}
__device__ int ids_are_64(const int* __restrict__ raw, int hi) {
    bool is64 = true;
    for (int i = 1; i < 32; i += 2) is64 = is64 && (raw[i] == 0);
    for (int i = 0; i < 32; i += 2) is64 = is64 && (raw[i] >= 0 && raw[i] < hi);
    return is64 ? 1 : 0;
}

// ---------- router stage 1: one block per sample (grid=32), fp64 exact ----------
__global__ __launch_bounds__(RHID) void router_probs_r24(
    const int* __restrict__ stage_ids,
    const int* __restrict__ view_ids,
    const float* __restrict__ stage_emb,
    const float* __restrict__ view_emb,
    const float* __restrict__ rw1,
    const float* __restrict__ rb1,
    const float* __restrict__ rw2,
    const float* __restrict__ rb2,
    float* __restrict__ out_probs,
    float* __restrict__ out_sel,
    int* __restrict__ sel_ws)
{
    const int b = blockIdx.x;
    const int t = threadIdx.x;
    __shared__ double z[2 * EEMB];
    __shared__ double h[RHID];
    __shared__ double lg[KEXP];
    __shared__ int sid_s, vid_s;
    if (t == 0) {
        const int s64 = ids_are_64(stage_ids, NSTAGE);
        const int v64 = ids_are_64(view_ids, NVIEW);
        sid_s = resolve_id_one(stage_ids, b, NSTAGE, s64);
        vid_s = resolve_id_one(view_ids, b, NVIEW, v64);
    }
    __syncthreads();
    const int sid = sid_s, vid = vid_s;
    z[t] = (t < EEMB) ? (double)stage_emb[sid * EEMB + t]
                      : (double)view_emb[vid * EEMB + (t - EEMB)];
    __syncthreads();
    double acc = (double)rb1[t];
    for (int i = 0; i < 2 * EEMB; ++i) acc += z[i] * (double)rw1[i * RHID + t];
    h[t] = fmax(acc, 0.0);
    __syncthreads();
    if (t < KEXP) {
        double a = (double)rb2[t];
        for (int i = 0; i < RHID; ++i) a += h[i] * (double)rw2[i * KEXP + t];
        lg[t] = a;
    }
    __syncthreads();
    if (t == 0) {
        double mx = lg[0]; int am = 0;
        for (int k = 1; k < KEXP; ++k) if (lg[k] > mx) { mx = lg[k]; am = k; }
        double p[KEXP]; double den = 0.0;
        for (int k = 0; k < KEXP; ++k) { p[k] = exp(lg[k] - mx); den += p[k]; }
        for (int k = 0; k < KEXP; ++k) out_probs[b * KEXP + k] = (float)(p[k] / den);
        out_sel[b] = (float)am;
        sel_ws[b] = am;
    }
}

__global__ void router_loss_r24(const float* __restrict__ probs,
                                const int* __restrict__ sel,
                                float* __restrict__ out_loss)
{
    if (threadIdx.x != 0) return;
    double loss = 0.0;
    for (int k = 0; k < KEXP; ++k) {
        double ps = 0.0; int fc = 0;
        for (int b = 0; b < BATCH; ++b) {
            ps += (double)probs[b * KEXP + k];
            fc += (sel[b] == k) ? 1 : 0;
        }
        loss += ((double)fc / (double)BATCH) * (ps / (double)BATCH);
    }
    out_loss[0] = (float)((double)KEXP * loss);
}

// ---------------- prep: f32 -> bf16 convert (x) ----------------
__global__ void cvt_f32_bf16_r24(const float* __restrict__ src,
                                 unsigned short* __restrict__ dst, size_t n)
{
    size_t i = (size_t)blockIdx.x * blockDim.x + threadIdx.x;
    size_t stride = (size_t)gridDim.x * blockDim.x;
    for (size_t j = i * 4; j < n; j += stride * 4) {
        float4 v = *(const float4*)(src + j);
        ushort4 o;
        o.x = f32_to_bf16_rne(v.x); o.y = f32_to_bf16_rne(v.y);
        o.z = f32_to_bf16_rne(v.z); o.w = f32_to_bf16_rne(v.w);
        *(ushort4*)(dst + j) = o;
    }
}

// ------ prep: 64x64 tiled transpose+convert src[e][R][C] f32 -> dst[e][C][R] bf16 ------
__global__ __launch_bounds__(512) void transpose_f32_bf16_r24(
    const float* __restrict__ src, unsigned short* __restrict__ dst, int R, int C)
{
    __shared__ float tile[64][65];
    const int e = blockIdx.z;
    const float* s = src + (size_t)e * R * C;
    unsigned short* d = dst + (size_t)e * R * C;
    const int c0 = blockIdx.x * 64, r0 = blockIdx.y * 64;
    const int tx = threadIdx.x, ty = threadIdx.y; // (64, 8)
    #pragma unroll
    for (int i = 0; i < 64; i += 8)
        tile[ty + i][tx] = s[(size_t)(r0 + ty + i) * C + (c0 + tx)];
    __syncthreads();
    #pragma unroll
    for (int i = 0; i < 64; i += 8)
        d[(size_t)(c0 + ty + i) * R + (r0 + tx)] = f32_to_bf16_rne(tile[tx][ty + i]);
}

// ======== m201-template GEMM: 256x256 / BK=64 / 8-wave / 4-phase-per-tile ========
// Best-measured configuration (r22: total 783us wall; ~364us/GEMM ~= 1.5x r17).
// LDS 128KB = 2 buf x 4 units of 16KB. Per tile: 4 phases of {ds_read quad
// (+B frags at q0) | stage 1 unit | bar | lgkm(0) | setprio 16 MFMA | bar};
// counted vmcnt(4) once per tile at ph3 (B(t+2) stays in flight; never 0 mid-loop).
// Swizzle/fragment/epilogue maps HW-verified rounds 8-22 (0 bank conflicts).

template<int MODE, int OBF>  // MODE 0: gelu(acc+bias); 1: acc+bias. OBF: 1 bf16 out, 0 f32 out
__global__ __launch_bounds__(512) void gemm_8p_r24(
    const unsigned short* __restrict__ Aall,
    const unsigned short* __restrict__ BTall,
    const float* __restrict__ biasAll,
    void* __restrict__ OutV,
    const int* __restrict__ sel, int g0,
    int M, int N, int K)
{
    const int bz = blockIdx.z;
    int e = sel[g0 + bz];
    e = e < 0 ? 0 : (e >= KEXP ? KEXP - 1 : e);
    const unsigned short* A  = Aall + (size_t)bz * M * K;
    const unsigned short* BT = BTall + (size_t)e * (size_t)N * K;
    const float* bias = biasAll + (size_t)e * N;

    __shared__ __align__(16) unsigned short lds[65536];   // 128 KB
    char* Lc = (char*)lds;

    const int tid  = threadIdx.x;
    const int lane = tid & 63;
    const int wave = tid >> 6;     // 0..7
    const int wr = wave >> 2;      // 0..1 : A-half / 128 output rows
    const int wc = wave & 3;       // 0..3 : 64 output cols
    const int fr = lane & 15;
    const int fq = lane >> 4;
    const int swz = fr & 7;

    const int brow = blockIdx.y * 256;
    const int bcol = blockIdx.x * 256;

    const int srow = lane >> 3;                          // 0..7
    const int scol = ((lane & 7) ^ (lane >> 3)) * 8;     // pre-swizzled source chunk (hw)

    const int NT = K >> 6;

    const int aSlot = wr * 16384;
    const int bSlot = 32768 + (wc >> 1) * 16384;
    const int c0off = ((0 + fq) ^ swz) * 16;
    const int c1off = ((4 + fq) ^ swz) * 16;

    const f32x4 zero = {0.f, 0.f, 0.f, 0.f};
    f32x4 acc[8][4];
    #pragma unroll
    for (int m = 0; m < 8; ++m)
        #pragma unroll
        for (int n = 0; n < 4; ++n) acc[m][n] = zero;

    auto STAGE = [&](int isB, int h, int t) {
        const int kh = t << 6;
        char* dbase = Lc + (t & 1) * 65536 + isB * 32768 + h * 16384 + wave * 1024;
        const unsigned short* sbase = isB ? (BT + (size_t)(bcol + h * 128) * K)
                                          : (A + (size_t)(brow + h * 128) * K);
        #pragma unroll
        for (int j = 0; j < 2; ++j) {
            const unsigned short* g = sbase + (size_t)(j * 64 + wave * 8 + srow) * K + (kh + scol);
            __builtin_amdgcn_global_load_lds(AS1C(g), AS3(dbase + j * 8192), 16, 0, 0);
        }
    };

    STAGE(0, 0, 0); STAGE(0, 1, 0);
    STAGE(1, 0, 0); STAGE(1, 1, 0);
    if (NT > 1) { STAGE(1, 0, 1); STAGE(1, 1, 1); }
    asm volatile("s_waitcnt vmcnt(4)" ::: "memory");
    __builtin_amdgcn_s_barrier();
    __builtin_amdgcn_sched_barrier(0);

    bf16x8 bfr[4][2];

    for (int t = 0; t < NT; ++t) {
        const int buf = (t & 1) * 65536;
        const int aB = buf + aSlot;
        const int bB = buf + bSlot;

        #pragma unroll
        for (int q = 0; q < 4; ++q) {
            bf16x8 af0k0, af0k1, af1k0, af1k1;
            {
                const int la0 = (2 * q + 0) * 16 + fr;
                const int la1 = (2 * q + 1) * 16 + fr;
                af0k0 = *(const bf16x8*)(Lc + aB + la0 * 128 + c0off);
                af0k1 = *(const bf16x8*)(Lc + aB + la0 * 128 + c1off);
                af1k0 = *(const bf16x8*)(Lc + aB + la1 * 128 + c0off);
                af1k1 = *(const bf16x8*)(Lc + aB + la1 * 128 + c1off);
            }
            if (q == 0) {
                #pragma unroll
                for (int n = 0; n < 4; ++n) {
                    const int lb = (wc & 1) * 64 + n * 16 + fr;
                    bfr[n][0] = *(const bf16x8*)(Lc + bB + lb * 128 + c0off);
                    bfr[n][1] = *(const bf16x8*)(Lc + bB + lb * 128 + c1off);
                }
            }
            if (q == 0)      { if (t + 1 < NT) STAGE(0, 0, t + 1); }
            else if (q == 1) { if (t + 1 < NT) STAGE(0, 1, t + 1); }
            else if (q == 2) { if (t + 2 < NT) STAGE(1, 0, t + 2); }
            else             { if (t + 2 < NT) STAGE(1, 1, t + 2); }
            if (q == 3) {
                if (t < NT - 2) asm volatile("s_waitcnt vmcnt(4)" ::: "memory");
                else            asm volatile("s_waitcnt vmcnt(0)" ::: "memory");
            }
            __builtin_amdgcn_sched_barrier(0);
            __builtin_amdgcn_s_barrier();
            asm volatile("s_waitcnt lgkmcnt(0)" ::: "memory");
            __builtin_amdgcn_sched_barrier(0);
            __builtin_amdgcn_s_setprio(1);
            {
                const int m0 = 2 * q, m1 = 2 * q + 1;
                #pragma unroll
                for (int n = 0; n < 4; ++n)
                    acc[m0][n] = __builtin_amdgcn_mfma_f32_16x16x32_bf16(af0k0, bfr[n][0], acc[m0][n], 0, 0, 0);
                #pragma unroll
                for (int n = 0; n < 4; ++n)
                    acc[m1][n] = __builtin_amdgcn_mfma_f32_16x16x32_bf16(af1k0, bfr[n][0], acc[m1][n], 0, 0, 0);
                #pragma unroll
                for (int n = 0; n < 4; ++n)
                    acc[m0][n] = __builtin_amdgcn_mfma_f32_16x16x32_bf16(af0k1, bfr[n][1], acc[m0][n], 0, 0, 0);
                #pragma unroll
                for (int n = 0; n < 4; ++n)
                    acc[m1][n] = __builtin_amdgcn_mfma_f32_16x16x32_bf16(af1k1, bfr[n][1], acc[m1][n], 0, 0, 0);
            }
            __builtin_amdgcn_s_setprio(0);
            __builtin_amdgcn_s_barrier();
        }
    }

    // epilogue: C/D col=lane&15, row=(lane>>4)*4+reg  [HW-verified rounds 8-22]
    #pragma unroll
    for (int m = 0; m < 8; ++m) {
        #pragma unroll
        for (int n = 0; n < 4; ++n) {
            #pragma unroll
            for (int r = 0; r < 4; ++r) {
                const int row = brow + wr * 128 + m * 16 + fq * 4 + r;
                const int col = bcol + wc * 64 + n * 16 + fr;
                float v = acc[m][n][r] + bias[col];
                if (MODE == 0) v = 0.5f * v * (1.0f + erff(v * 0.70710678118654752f));
                const size_t idx = (size_t)bz * M * N + (size_t)row * N + col;
                if (OBF) ((unsigned short*)OutV)[idx] = f32_to_bf16_rne(v);
                else     ((float*)OutV)[idx] = v;
            }
        }
    }
}

extern "C" void kernel_launch(void* const* d_in, const int* in_sizes, int n_in,
                              void* d_out, int out_size, void* d_ws, size_t ws_size,
                              hipStream_t stream)
{
    const float* x         = (const float*)d_in[0];
    const int*   stage_ids = (const int*)d_in[1];
    const int*   view_ids  = (const int*)d_in[2];
    const float* stage_emb = (const float*)d_in[3];
    const float* view_emb  = (const float*)d_in[4];
    const float* rw1       = (const float*)d_in[5];
    const float* rb1       = (const float*)d_in[6];
    const float* rw2       = (const float*)d_in[7];
    const float* rb2       = (const float*)d_in[8];
    const float* w1        = (const float*)d_in[9];
    const float* b1        = (const float*)d_in[10];
    const float* w2        = (const float*)d_in[11];
    const float* b2        = (const float*)d_in[12];

    float* out_f = (float*)d_out;
    const size_t OUT_ELEMS = (size_t)BATCH * TSEQ * DMODEL;

    const size_t MB64 = 67108864ull;
    char* ws = (char*)d_ws;
    int* sel_ws            = (int*)ws;
    unsigned short* x_bf   = (unsigned short*)(ws + 4096);
    unsigned short* w1T    = (unsigned short*)(ws + 4096 + MB64);
    unsigned short* w2T    = (unsigned short*)(ws + 4096 + 2 * MB64);
    unsigned short* h_bf   = (unsigned short*)(ws + 4096 + 3 * MB64);

    int grp = 1;
    {
        const size_t base = 4096 + 3 * MB64;
        const size_t avail = ws_size > base ? ws_size - base : 0;
        for (int g = 32; g >= 1; g >>= 1) {
            if ((size_t)g * TSEQ * FFFN * 2 <= avail) { grp = g; break; }
        }
    }

    router_probs_r24<<<BATCH, RHID, 0, stream>>>(stage_ids, view_ids, stage_emb, view_emb,
        rw1, rb1, rw2, rb2,
        out_f + OUT_ELEMS,
        out_f + OUT_ELEMS + BATCH * KEXP,
        sel_ws);
    router_loss_r24<<<1, 64, 0, stream>>>(out_f + OUT_ELEMS, sel_ws,
        out_f + OUT_ELEMS + BATCH * KEXP + BATCH);

    cvt_f32_bf16_r24<<<2048, 256, 0, stream>>>(x, x_bf, (size_t)BATCH * TSEQ * DMODEL);
    dim3 tb(64, 8);
    transpose_f32_bf16_r24<<<dim3(FFFN / 64, DMODEL / 64, KEXP), tb, 0, stream>>>(w1, w1T, DMODEL, FFFN);
    transpose_f32_bf16_r24<<<dim3(DMODEL / 64, FFFN / 64, KEXP), tb, 0, stream>>>(w2, w2T, FFFN, DMODEL);

    for (int g0 = 0; g0 < BATCH; g0 += grp) {
        // h = gelu(x @ w1[e]^T + b1[e]) : M=1024, N=4096, K=1024 -> bf16
        gemm_8p_r24<0, 1><<<dim3(FFFN / 256, TSEQ / 256, grp), 512, 0, stream>>>(
            x_bf + (size_t)g0 * TSEQ * DMODEL, w1T, b1,
            (void*)h_bf, sel_ws, g0, TSEQ, FFFN, DMODEL);
        // out = h @ w2[e]^T + b2[e]     : M=1024, N=1024, K=4096 -> f32
        gemm_8p_r24<1, 0><<<dim3(DMODEL / 256, TSEQ / 256, grp), 512, 0, stream>>>(
            h_bf, w2T, b2,
            (void*)(out_f + (size_t)g0 * TSEQ * DMODEL), sel_ws, g0, TSEQ, DMODEL, FFFN);
    }
}